// Round 1
// baseline (26.659 us; speedup 1.0000x reference)
//
#include <hip/hip_runtime.h>
#include <hip/hip_bf16.h>

// out[b,d] = ortho[d,0]*c0[o]*ns[b,0] + ortho[d,1]*c1[o]*ns[b,1] + mu[o,d]
//   where o = idx[b], c_r[o] = var[o,r]^2.  R=2, D=128, NOBJ=9.
// Memory-bound: dominated by the 64 MB output write.

#define VAE_D    128
#define VAE_R    2
#define VAE_NOBJ 9
#define ROWS_PER_BLOCK 8   // 8 rows * 32 lanes = 256 threads

__global__ __launch_bounds__(256)
void vae_embed_kernel(const int* __restrict__ idx,
                      const float* __restrict__ ns,      // [B, 128]
                      const float* __restrict__ ortho,   // [128, 128] row-major
                      const float* __restrict__ mu,      // [9, 128]
                      const float* __restrict__ var,     // [9, 2]
                      float* __restrict__ out,           // [B, 128]
                      int B)
{
    __shared__ float s_mu[VAE_NOBJ][VAE_D];   // 4608 B
    __shared__ float s_oc[VAE_D][2];          // ortho[:,0], ortho[:,1] interleaved
    __shared__ float s_c[VAE_NOBJ][2];        // var^2

    const int t = threadIdx.x;

    // Cooperative table staging (tiny; L2-hot after first block).
    for (int i = t; i < VAE_NOBJ * VAE_D; i += 256)
        s_mu[i >> 7][i & 127] = mu[i];
    for (int i = t; i < VAE_D; i += 256) {
        s_oc[i][0] = ortho[i * VAE_D + 0];
        s_oc[i][1] = ortho[i * VAE_D + 1];
    }
    if (t < VAE_NOBJ * VAE_R) {
        float v = var[t];
        s_c[t >> 1][t & 1] = v * v;
    }
    __syncthreads();

    const int row_in_blk = t >> 5;          // 0..7
    const int lane       = t & 31;          // 0..31
    const int b = blockIdx.x * ROWS_PER_BLOCK + row_in_blk;
    if (b >= B) return;

    const int o = idx[b];                                   // broadcast load
    const float2 n01 = *reinterpret_cast<const float2*>(ns + (size_t)b * VAE_D);
    const float a0 = s_c[o][0] * n01.x;
    const float a1 = s_c[o][1] * n01.y;

    const int d0 = lane << 2;               // 4 outputs per lane

    // mu row as float4 (ds_read_b128, conflict-light)
    const float4 m = *reinterpret_cast<const float4*>(&s_mu[o][d0]);
    // ortho column pairs for d0..d0+3: 8 contiguous floats -> two float4s
    const float4 oa = *reinterpret_cast<const float4*>(&s_oc[d0][0]);     // o[d0][0],o[d0][1],o[d0+1][0],o[d0+1][1]
    const float4 ob = *reinterpret_cast<const float4*>(&s_oc[d0 + 2][0]);

    float4 r;
    r.x = fmaf(oa.x, a0, fmaf(oa.y, a1, m.x));
    r.y = fmaf(oa.z, a0, fmaf(oa.w, a1, m.y));
    r.z = fmaf(ob.x, a0, fmaf(ob.y, a1, m.z));
    r.w = fmaf(ob.z, a0, fmaf(ob.w, a1, m.w));

    *reinterpret_cast<float4*>(out + (size_t)b * VAE_D + d0) = r;
}

extern "C" void kernel_launch(void* const* d_in, const int* in_sizes, int n_in,
                              void* d_out, int out_size, void* d_ws, size_t ws_size,
                              hipStream_t stream)
{
    // setup_inputs order: img[ B,4 ], random_int[B], normal_sample[B,128],
    //                     orthogonal_set[128,128], mu_[9,128], var_[9,2]
    const int*   idx   = (const int*)  d_in[1];
    const float* ns    = (const float*)d_in[2];
    const float* ortho = (const float*)d_in[3];
    const float* mu    = (const float*)d_in[4];
    const float* var   = (const float*)d_in[5];
    float* out = (float*)d_out;

    const int B = in_sizes[1];
    const int grid = (B + ROWS_PER_BLOCK - 1) / ROWS_PER_BLOCK;

    vae_embed_kernel<<<grid, 256, 0, stream>>>(idx, ns, ortho, mu, var, out, B);
}

// Round 2
// 22.088 us; speedup vs baseline: 1.2069x; 1.2069x over previous
//
#include <hip/hip_runtime.h>
#include <hip/hip_bf16.h>

// out[b,d] = ortho[d,0]*(var[o,0]^2*ns[b,0]) + ortho[d,1]*(var[o,1]^2*ns[b,1]) + mu[o,d]
//   o = idx[b].  D=128, R=2, NOBJ=9.  img unused.
// Pure streaming kernel: ~67 MB write + ~18 MB fetch -> HBM-write-bound.
// No LDS: mu (4.6 KB), ortho cols (1 KB), var (72 B) are L1-resident;
// per-block LDS staging + barrier was the round-1 bottleneck.

#define VAE_D 128

__global__ __launch_bounds__(256)
void vae_embed_kernel(const int* __restrict__ idx,
                      const float* __restrict__ ns,      // [B, 128]
                      const float* __restrict__ ortho,   // [128, 128] row-major
                      const float* __restrict__ mu,      // [9, 128]
                      const float* __restrict__ var,     // [9, 2]
                      float* __restrict__ out,           // [B, 128]
                      int B)
{
    const int t    = threadIdx.x;
    const int lane = t & 31;            // 32 lanes cover one row (4 floats each)
    const int grp  = t >> 5;            // 8 row-slots per block
    const int d0   = lane << 2;

    // Loop-invariant per-thread: ortho[d0+j][0:2], j=0..3 (L1-hot after warmup)
    const float2 oc0 = *reinterpret_cast<const float2*>(ortho + (size_t)(d0 + 0) * VAE_D);
    const float2 oc1 = *reinterpret_cast<const float2*>(ortho + (size_t)(d0 + 1) * VAE_D);
    const float2 oc2 = *reinterpret_cast<const float2*>(ortho + (size_t)(d0 + 2) * VAE_D);
    const float2 oc3 = *reinterpret_cast<const float2*>(ortho + (size_t)(d0 + 3) * VAE_D);

    const int groups  = B >> 3;                                  // row-groups of 8
    const int per_blk = (groups + gridDim.x - 1) / gridDim.x;    // contiguous chunk
    const int g0 = blockIdx.x * per_blk;
    const int g1 = (g0 + per_blk < groups) ? (g0 + per_blk) : groups;

    #pragma unroll 4
    for (int g = g0; g < g1; ++g) {
        const int b = (g << 3) + grp;
        const int o = idx[b];                                    // broadcast dword
        const float2 n01 = *reinterpret_cast<const float2*>(ns + (size_t)b * VAE_D);
        const float2 v   = *reinterpret_cast<const float2*>(var + (size_t)o * 2);
        const float a0 = v.x * v.x * n01.x;
        const float a1 = v.y * v.y * n01.y;

        const float4 m = *reinterpret_cast<const float4*>(mu + (size_t)o * VAE_D + d0);

        float4 r;
        r.x = fmaf(oc0.x, a0, fmaf(oc0.y, a1, m.x));
        r.y = fmaf(oc1.x, a0, fmaf(oc1.y, a1, m.y));
        r.z = fmaf(oc2.x, a0, fmaf(oc2.y, a1, m.z));
        r.w = fmaf(oc3.x, a0, fmaf(oc3.y, a1, m.w));

        *reinterpret_cast<float4*>(out + (size_t)b * VAE_D + d0) = r;
    }
}

extern "C" void kernel_launch(void* const* d_in, const int* in_sizes, int n_in,
                              void* d_out, int out_size, void* d_ws, size_t ws_size,
                              hipStream_t stream)
{
    // inputs: img[B,4], random_int[B], normal_sample[B,128],
    //         orthogonal_set[128,128], mu_[9,128], var_[9,2]
    const int*   idx   = (const int*)  d_in[1];
    const float* ns    = (const float*)d_in[2];
    const float* ortho = (const float*)d_in[3];
    const float* mu    = (const float*)d_in[4];
    const float* var   = (const float*)d_in[5];
    float* out = (float*)d_out;

    const int B = in_sizes[1];
    const int groups = B >> 3;                  // 16384 for B=131072
    int grid = 2048;                            // 64 contiguous rows per block
    if (grid > groups) grid = groups;

    vae_embed_kernel<<<grid, 256, 0, stream>>>(idx, ns, ortho, mu, var, out, B);
}

// Round 4
// 19.971 us; speedup vs baseline: 1.3349x; 1.1060x over previous
//
#include <hip/hip_runtime.h>
#include <hip/hip_bf16.h>

// out[b,d] = ortho[d,0]*(var[o,0]^2*ns[b,0]) + ortho[d,1]*(var[o,1]^2*ns[b,1]) + mu[o,d]
//   o = idx[b].  D=128, R=2, NOBJ=9.  img unused.
// HBM-write-bound streaming kernel (~77 MB traffic -> ~12 us floor).
// R4: same 8-deep software pipeline as R3; nontemporal store via clang
// ext_vector_type (HIP float4 class type is rejected by the builtin).

#define VAE_D 128

typedef float f32x4 __attribute__((ext_vector_type(4)));

__global__ __launch_bounds__(256)
void vae_embed_kernel(const int* __restrict__ idx,
                      const float* __restrict__ ns,      // [B, 128]
                      const float* __restrict__ ortho,   // [128, 128] row-major
                      const float* __restrict__ mu,      // [9, 128]
                      const float* __restrict__ var,     // [9, 2]
                      float* __restrict__ out,           // [B, 128]
                      int B)
{
    const int t    = threadIdx.x;
    const int lane = t & 31;            // 32 lanes cover one row (4 floats each)
    const int grp  = t >> 5;            // 8 row-slots per block
    const int d0   = lane << 2;

    // Loop-invariant ortho column pairs (L1/L2-hot after warmup).
    const float2 oc0 = *reinterpret_cast<const float2*>(ortho + (size_t)(d0 + 0) * VAE_D);
    const float2 oc1 = *reinterpret_cast<const float2*>(ortho + (size_t)(d0 + 1) * VAE_D);
    const float2 oc2 = *reinterpret_cast<const float2*>(ortho + (size_t)(d0 + 2) * VAE_D);
    const float2 oc3 = *reinterpret_cast<const float2*>(ortho + (size_t)(d0 + 3) * VAE_D);

    const int groups = B >> 3;                 // row-groups of 8
    const int g0 = blockIdx.x * 8;             // 8 groups per block (grid sized so)

    if (g0 + 8 <= groups) {
        // ---- fast path: fully static 8-deep pipeline ----
        int    o[8];
        float2 n[8];

        #pragma unroll
        for (int u = 0; u < 8; ++u) {          // phase 1: 8 independent idx loads
            const int b = ((g0 + u) << 3) + grp;
            o[u] = idx[b];
        }
        #pragma unroll
        for (int u = 0; u < 8; ++u) {          // phase 2: 8 independent ns loads
            const int b = ((g0 + u) << 3) + grp;
            n[u] = *reinterpret_cast<const float2*>(ns + (size_t)b * VAE_D);
        }
        #pragma unroll
        for (int u = 0; u < 8; ++u) {          // phase 3: dependent gather+compute+store
            const int b = ((g0 + u) << 3) + grp;
            const float2 v = *reinterpret_cast<const float2*>(var + o[u] * 2);
            const float a0 = v.x * v.x * n[u].x;
            const float a1 = v.y * v.y * n[u].y;
            const float4 m = *reinterpret_cast<const float4*>(mu + (size_t)o[u] * VAE_D + d0);
            f32x4 r;
            r.x = fmaf(oc0.x, a0, fmaf(oc0.y, a1, m.x));
            r.y = fmaf(oc1.x, a0, fmaf(oc1.y, a1, m.y));
            r.z = fmaf(oc2.x, a0, fmaf(oc2.y, a1, m.z));
            r.w = fmaf(oc3.x, a0, fmaf(oc3.y, a1, m.w));
            __builtin_nontemporal_store(r,
                reinterpret_cast<f32x4*>(out + (size_t)b * VAE_D + d0));
        }
    } else {
        // ---- generic tail (unused for B=131072 but keeps kernel correct) ----
        for (int g = g0; g < groups; ++g) {
            const int b = (g << 3) + grp;
            const int o = idx[b];
            const float2 n01 = *reinterpret_cast<const float2*>(ns + (size_t)b * VAE_D);
            const float2 v   = *reinterpret_cast<const float2*>(var + o * 2);
            const float a0 = v.x * v.x * n01.x;
            const float a1 = v.y * v.y * n01.y;
            const float4 m = *reinterpret_cast<const float4*>(mu + (size_t)o * VAE_D + d0);
            float4 r;
            r.x = fmaf(oc0.x, a0, fmaf(oc0.y, a1, m.x));
            r.y = fmaf(oc1.x, a0, fmaf(oc1.y, a1, m.y));
            r.z = fmaf(oc2.x, a0, fmaf(oc2.y, a1, m.z));
            r.w = fmaf(oc3.x, a0, fmaf(oc3.y, a1, m.w));
            *reinterpret_cast<float4*>(out + (size_t)b * VAE_D + d0) = r;
        }
    }
}

extern "C" void kernel_launch(void* const* d_in, const int* in_sizes, int n_in,
                              void* d_out, int out_size, void* d_ws, size_t ws_size,
                              hipStream_t stream)
{
    // inputs: img[B,4], random_int[B], normal_sample[B,128],
    //         orthogonal_set[128,128], mu_[9,128], var_[9,2]
    const int*   idx   = (const int*)  d_in[1];
    const float* ns    = (const float*)d_in[2];
    const float* ortho = (const float*)d_in[3];
    const float* mu    = (const float*)d_in[4];
    const float* var   = (const float*)d_in[5];
    float* out = (float*)d_out;

    const int B = in_sizes[1];
    const int groups = B >> 3;                         // 16384 for B=131072
    const int grid = (groups + 7) / 8;                 // 8 groups (64 rows) per block

    vae_embed_kernel<<<grid, 256, 0, stream>>>(idx, ns, ortho, mu, var, out, B);
}